// Round 5
// baseline (1756.327 us; speedup 1.0000x reference)
//
#include <hip/hip_runtime.h>
#include <hip/hip_bf16.h>

#define BN_EPS 1e-5f

// Static device scratch: 2*N + 2*N*64 + 128 floats (N=100000) = 52 MB.
#define N_MAX 100000
__device__ float g_ws[2 * N_MAX + 2 * N_MAX * 64 + 128];

// ---------------- degrees ----------------
__global__ void k_degrees(const int* __restrict__ src, const int* __restrict__ dst,
                          float* __restrict__ deg_s, float* __restrict__ deg_d, int E) {
    int e = blockIdx.x * blockDim.x + threadIdx.x;
    if (e < E) {
        atomicAdd(&deg_s[src[e]], 1.0f);
        atomicAdd(&deg_d[dst[e]], 1.0f);
    }
}

__global__ void k_isqrt(float* __restrict__ a, float* __restrict__ b, int n) {
    int i = blockIdx.x * blockDim.x + threadIdx.x;
    if (i < n) {
        a[i] = rsqrtf(fmaxf(a[i], 1.0f));
        b[i] = rsqrtf(fmaxf(b[i], 1.0f));
    }
}

// ---------------- dense GEMM: C[n x KOUT] = (X * rowscale) @ W ----------------
template<int KIN, int KOUT, int ROWS>
__global__ __launch_bounds__(256)
void k_gemm(const float* __restrict__ X, const float* __restrict__ rowscale,
            const float* __restrict__ W, float* __restrict__ C, int n) {
    __shared__ float Ws[KIN * KOUT];
    __shared__ float Xs[ROWS][KIN];
    const int tid = threadIdx.x;
    for (int i = tid; i < KIN * KOUT; i += 256) Ws[i] = W[i];
    const int row0 = blockIdx.x * ROWS;
    for (int i = tid; i < ROWS * KIN; i += 256) {
        int r = i / KIN, k = i % KIN;
        int row = row0 + r;
        float v = 0.0f;
        if (row < n) {
            v = X[(size_t)row * KIN + k];
            if (rowscale) v *= rowscale[row];
        }
        Xs[r][k] = v;
    }
    __syncthreads();
    for (int idx = tid; idx < ROWS * KOUT; idx += 256) {
        int r = idx / KOUT, c = idx % KOUT;
        int row = row0 + r;
        if (row >= n) continue;
        float acc = 0.0f;
#pragma unroll
        for (int k = 0; k < KIN; ++k) acc = fmaf(Xs[r][k], Ws[k * KOUT + c], acc);
        C[(size_t)row * KOUT + c] = acc;
    }
}

// ---------------- edge scatter-add: out[dst] += in[src] * (rowscale?) ----------------
template<int F>
__global__ __launch_bounds__(256)
void k_scatter(const int* __restrict__ src, const int* __restrict__ dst,
               const float* __restrict__ in, const float* __restrict__ rowscale,
               float* __restrict__ out, int E) {
    unsigned gid = blockIdx.x * 256u + threadIdx.x;
    unsigned e = gid / F;
    if (e >= (unsigned)E) return;
    unsigned f = gid - e * F;
    int s = src[e], d = dst[e];
    float v = in[(size_t)s * F + f];
    if (rowscale) v *= rowscale[s];
    atomicAdd(&out[(size_t)d * F + f], v);
}

// ---------------- BatchNorm stats over h = A*isq + bias (64 features) ----------------
__global__ __launch_bounds__(256)
void k_bn_stats(const float* __restrict__ A, const float* __restrict__ isq,
                const float* __restrict__ bias,
                float* __restrict__ stats, int n) {
    const int f = threadIdx.x & 63;
    const int sub = threadIdx.x >> 6;
    const float b = bias[f];
    float s = 0.0f, q = 0.0f;
    for (int i = blockIdx.x * 4 + sub; i < n; i += gridDim.x * 4) {
        float h = A[(size_t)i * 64 + f] * isq[i] + b;
        s += h;
        q += h * h;
    }
    __shared__ float ls[4][64], lq[4][64];
    ls[sub][f] = s; lq[sub][f] = q;
    __syncthreads();
    if (sub == 0) {
        s = ls[0][f] + ls[1][f] + ls[2][f] + ls[3][f];
        q = lq[0][f] + lq[1][f] + lq[2][f] + lq[3][f];
        atomicAdd(&stats[f], s);
        atomicAdd(&stats[64 + f], q);
    }
}

// ---------------- BatchNorm apply + ReLU ----------------
__global__ __launch_bounds__(256)
void k_bn_apply(const float* __restrict__ A, const float* __restrict__ isq,
                const float* __restrict__ bias,
                const float* __restrict__ gamma,
                const float* __restrict__ beta,
                const float* __restrict__ stats,
                float* __restrict__ B, int n) {
    unsigned gid = blockIdx.x * 256u + threadIdx.x;
    unsigned i = gid >> 6;
    if (i >= (unsigned)n) return;
    unsigned f = gid & 63u;
    const float invn = 1.0f / (float)n;
    float mu = stats[f] * invn;
    float var = stats[64 + f] * invn - mu * mu;
    float h = A[(size_t)i * 64 + f] * isq[i] + bias[f];
    float y = gamma[f] * (h - mu) * rsqrtf(var + BN_EPS) + beta[f];
    B[(size_t)i * 64 + f] = fmaxf(y, 0.0f);
}

// ---------------- final: out = f32(A*isq + bias), F=47 ----------------
__global__ __launch_bounds__(256)
void k_final(const float* __restrict__ A, const float* __restrict__ isq,
             const float* __restrict__ bias,
             float* __restrict__ out, int n) {
    unsigned gid = blockIdx.x * 256u + threadIdx.x;
    if (gid >= (unsigned)n * 47u) return;
    unsigned i = gid / 47u;
    unsigned f = gid - i * 47u;
    out[gid] = A[(size_t)i * 47 + f] * isq[i] + bias[f];
}

extern "C" void kernel_launch(void* const* d_in, const int* in_sizes, int n_in,
                              void* d_out, int out_size, void* d_ws, size_t ws_size,
                              hipStream_t stream) {
    const float* feat = (const float*)d_in[0];
    const int* src  = (const int*)d_in[1];
    const int* dst  = (const int*)d_in[2];
    const float* W0  = (const float*)d_in[3];
    const float* b0  = (const float*)d_in[4];
    const float* W1  = (const float*)d_in[5];
    const float* b1  = (const float*)d_in[6];
    const float* W2  = (const float*)d_in[7];
    const float* b2  = (const float*)d_in[8];
    const float* g0  = (const float*)d_in[9];
    const float* be0 = (const float*)d_in[10];
    const float* g1  = (const float*)d_in[11];
    const float* be1 = (const float*)d_in[12];

    const int n = out_size / 47;       // 100000 nodes (robust to in_sizes units)
    const int E = in_sizes[1];         // 1600000 edges

    float* ws = nullptr;
    hipGetSymbolAddress((void**)&ws, HIP_SYMBOL(g_ws));
    float* isq_s = ws;                       // N
    float* isq_d = ws + n;                   // N
    float* buf1  = ws + 2 * (size_t)n;       // N*64
    float* buf2  = buf1 + (size_t)n * 64;    // N*64
    float* stats = buf2 + (size_t)n * 64;    // 128

    // degrees -> isqrt
    hipMemsetAsync(isq_s, 0, 2 * (size_t)n * sizeof(float), stream);
    k_degrees<<<(E + 255) / 256, 256, 0, stream>>>(src, dst, isq_s, isq_d, E);
    k_isqrt<<<(n + 255) / 256, 256, 0, stream>>>(isq_s, isq_d, n);

    // ---- Layer 0: GEMM first (128->64), then aggregate ----
    k_gemm<128, 64, 16><<<(n + 15) / 16, 256, 0, stream>>>(feat, isq_s, W0, buf1, n);
    hipMemsetAsync(buf2, 0, (size_t)n * 64 * sizeof(float), stream);
    k_scatter<64><<<(int)(((size_t)E * 64 + 255) / 256), 256, 0, stream>>>(src, dst, buf1, nullptr, buf2, E);
    hipMemsetAsync(stats, 0, 128 * sizeof(float), stream);
    k_bn_stats<<<512, 256, 0, stream>>>(buf2, isq_d, b0, stats, n);
    k_bn_apply<<<(int)(((size_t)n * 64 + 255) / 256), 256, 0, stream>>>(buf2, isq_d, b0, g0, be0, stats, buf1, n);

    // ---- Layer 1: aggregate first, then GEMM (64->64) ----
    hipMemsetAsync(buf2, 0, (size_t)n * 64 * sizeof(float), stream);
    k_scatter<64><<<(int)(((size_t)E * 64 + 255) / 256), 256, 0, stream>>>(src, dst, buf1, isq_s, buf2, E);
    k_gemm<64, 64, 16><<<(n + 15) / 16, 256, 0, stream>>>(buf2, nullptr, W1, buf1, n);
    hipMemsetAsync(stats, 0, 128 * sizeof(float), stream);
    k_bn_stats<<<512, 256, 0, stream>>>(buf1, isq_d, b1, stats, n);
    k_bn_apply<<<(int)(((size_t)n * 64 + 255) / 256), 256, 0, stream>>>(buf1, isq_d, b1, g1, be1, stats, buf2, n);

    // ---- Layer 2: GEMM first (64->47), then aggregate ----
    k_gemm<64, 47, 16><<<(n + 15) / 16, 256, 0, stream>>>(buf2, isq_s, W2, buf1, n);
    hipMemsetAsync(buf2, 0, (size_t)n * 47 * sizeof(float), stream);
    k_scatter<47><<<(int)(((size_t)E * 47 + 255) / 256), 256, 0, stream>>>(src, dst, buf1, nullptr, buf2, E);
    k_final<<<(int)(((size_t)n * 47 + 255) / 256), 256, 0, stream>>>(buf2, isq_d, b2, (float*)d_out, n);
}

// Round 6
// 983.969 us; speedup vs baseline: 1.7849x; 1.7849x over previous
//
#include <hip/hip_runtime.h>
#include <hip/hip_bf16.h>

#define BN_EPS 1e-5f
#define N_MAX 100000
#define E_MAX 1600000

// Static device scratch (d_ws ignored; proven safe in R4/R5).
// floats: isq_s N, isq_d N, buf1 64N, buf2 64N, stats 256
__device__ float g_wsf[130 * N_MAX + 256];
// ints: deg_s N, deg_d N, cnt N, row_ptr N+1, col E
__device__ int   g_wsi[4 * N_MAX + 1 + E_MAX];

// ---------------- degree histogram (int atomics) ----------------
__global__ void k_hist(const int* __restrict__ src, const int* __restrict__ dst,
                       int* __restrict__ deg_s, int* __restrict__ deg_d, int E) {
    int e = blockIdx.x * 256 + threadIdx.x;
    if (e < E) {
        atomicAdd(&deg_s[src[e]], 1);
        atomicAdd(&deg_d[dst[e]], 1);
    }
}

// ---------------- single-block exclusive scan: row_ptr[0..n] ----------------
__global__ __launch_bounds__(1024)
void k_scan(const int* __restrict__ deg, int* __restrict__ row_ptr, int n) {
    __shared__ int sums[1024];
    const int tid = threadIdx.x;
    const int chunk = (n + 1023) >> 10;
    const int beg = tid * chunk;
    const int end = min(beg + chunk, n);
    int s = 0;
    for (int i = beg; i < end; ++i) s += deg[i];
    sums[tid] = s;
    __syncthreads();
    for (int off = 1; off < 1024; off <<= 1) {          // Hillis-Steele inclusive
        int v = (tid >= off) ? sums[tid - off] : 0;
        __syncthreads();
        sums[tid] += v;
        __syncthreads();
    }
    int excl = (tid == 0) ? 0 : sums[tid - 1];
    for (int i = beg; i < end; ++i) { row_ptr[i] = excl; excl += deg[i]; }
    if (tid == 0) row_ptr[n] = sums[1023];
}

// ---------------- CSR fill (by dst) ----------------
__global__ void k_fill(const int* __restrict__ src, const int* __restrict__ dst,
                       const int* __restrict__ row_ptr, int* __restrict__ cnt,
                       int* __restrict__ col, int E) {
    int e = blockIdx.x * 256 + threadIdx.x;
    if (e < E) {
        int d = dst[e];
        int slot = atomicAdd(&cnt[d], 1);
        col[row_ptr[d] + slot] = src[e];
    }
}

// ---------------- D^{-1/2} from int degrees ----------------
__global__ void k_isqrt(const int* __restrict__ deg_s, const int* __restrict__ deg_d,
                        float* __restrict__ isq_s, float* __restrict__ isq_d, int n) {
    int i = blockIdx.x * 256 + threadIdx.x;
    if (i < n) {
        isq_s[i] = rsqrtf(fmaxf((float)deg_s[i], 1.0f));
        isq_d[i] = rsqrtf(fmaxf((float)deg_d[i], 1.0f));
    }
}

// ---------------- pull aggregation, F=64: one wave per node ----------------
// SB: epilogue out = acc*isq_d[d] + bias[f]; else raw acc.
template<bool SB>
__global__ __launch_bounds__(256)
void k_agg64(const int* __restrict__ row_ptr, const int* __restrict__ col,
             const float* __restrict__ in, const float* __restrict__ isq_d,
             const float* __restrict__ bias, float* __restrict__ out, int n) {
    const int d = blockIdx.x * 4 + (threadIdx.x >> 6);
    const int f = threadIdx.x & 63;
    if (d >= n) return;
    const int beg = row_ptr[d], end = row_ptr[d + 1];
    float acc = 0.0f;
    int e = beg;
    for (; e + 4 <= end; e += 4) {                 // 4 outstanding row loads
        int s0 = col[e], s1 = col[e + 1], s2 = col[e + 2], s3 = col[e + 3];
        float v0 = in[(size_t)s0 * 64 + f];
        float v1 = in[(size_t)s1 * 64 + f];
        float v2 = in[(size_t)s2 * 64 + f];
        float v3 = in[(size_t)s3 * 64 + f];
        acc += (v0 + v1) + (v2 + v3);
    }
    for (; e < end; ++e) acc += in[(size_t)col[e] * 64 + f];
    if (SB) out[(size_t)d * 64 + f] = acc * isq_d[d] + bias[f];
    else    out[(size_t)d * 64 + f] = acc;
}

// ---------------- dense GEMM: C = (X * rowscale?) @ W (+ bias?) ----------------
template<int KIN, int KOUT, int ROWS, bool BIAS>
__global__ __launch_bounds__(256)
void k_gemm(const float* __restrict__ X, const float* __restrict__ rowscale,
            const float* __restrict__ W, const float* __restrict__ bias,
            float* __restrict__ C, int n) {
    __shared__ float Ws[KIN * KOUT];
    __shared__ float Xs[ROWS][KIN];
    const int tid = threadIdx.x;
    for (int i = tid; i < KIN * KOUT; i += 256) Ws[i] = W[i];
    const int row0 = blockIdx.x * ROWS;
    for (int i = tid; i < ROWS * KIN; i += 256) {
        int r = i / KIN, k = i % KIN;
        int row = row0 + r;
        float v = 0.0f;
        if (row < n) {
            v = X[(size_t)row * KIN + k];
            if (rowscale) v *= rowscale[row];
        }
        Xs[r][k] = v;
    }
    __syncthreads();
    for (int idx = tid; idx < ROWS * KOUT; idx += 256) {
        int r = idx / KOUT, c = idx % KOUT;
        int row = row0 + r;
        if (row >= n) continue;
        float acc = 0.0f;
#pragma unroll
        for (int k = 0; k < KIN; ++k) acc = fmaf(Xs[r][k], Ws[k * KOUT + c], acc);
        if (BIAS) acc += bias[c];
        C[(size_t)row * KOUT + c] = acc;
    }
}

// ---------------- BN stats: sum/sumsq of A columns (64 feats) ----------------
__global__ __launch_bounds__(256)
void k_bn_stats(const float* __restrict__ A, float* __restrict__ stats, int n) {
    const int f = threadIdx.x & 63;
    const int sub = threadIdx.x >> 6;
    float s = 0.0f, q = 0.0f;
    for (int i = blockIdx.x * 4 + sub; i < n; i += gridDim.x * 4) {
        float h = A[(size_t)i * 64 + f];
        s += h;
        q += h * h;
    }
    __shared__ float ls[4][64], lq[4][64];
    ls[sub][f] = s; lq[sub][f] = q;
    __syncthreads();
    if (sub == 0) {
        s = ls[0][f] + ls[1][f] + ls[2][f] + ls[3][f];
        q = lq[0][f] + lq[1][f] + lq[2][f] + lq[3][f];
        atomicAdd(&stats[f], s);
        atomicAdd(&stats[64 + f], q);
    }
}

// ---------------- BN apply + ReLU, folded next-layer outscale ----------------
__global__ __launch_bounds__(256)
void k_bn_apply(const float* __restrict__ A, const float* __restrict__ gamma,
                const float* __restrict__ beta, const float* __restrict__ stats,
                const float* __restrict__ outscale, float* __restrict__ B, int n) {
    unsigned gid = blockIdx.x * 256u + threadIdx.x;
    unsigned i = gid >> 6;
    if (i >= (unsigned)n) return;
    unsigned f = gid & 63u;
    const float invn = 1.0f / (float)n;
    float mu = stats[f] * invn;
    float var = stats[64 + f] * invn - mu * mu;
    float h = A[(size_t)i * 64 + f];
    float y = gamma[f] * (h - mu) * rsqrtf(var + BN_EPS) + beta[f];
    B[(size_t)i * 64 + f] = fmaxf(y, 0.0f) * outscale[i];
}

extern "C" void kernel_launch(void* const* d_in, const int* in_sizes, int n_in,
                              void* d_out, int out_size, void* d_ws, size_t ws_size,
                              hipStream_t stream) {
    const float* feat = (const float*)d_in[0];
    const int* src  = (const int*)d_in[1];
    const int* dst  = (const int*)d_in[2];
    const float* W0  = (const float*)d_in[3];
    const float* b0  = (const float*)d_in[4];
    const float* W1  = (const float*)d_in[5];
    const float* b1  = (const float*)d_in[6];
    const float* W2  = (const float*)d_in[7];
    const float* b2  = (const float*)d_in[8];
    const float* g0  = (const float*)d_in[9];
    const float* be0 = (const float*)d_in[10];
    const float* g1  = (const float*)d_in[11];
    const float* be1 = (const float*)d_in[12];

    const int n = out_size / 47;       // 100000
    const int E = in_sizes[1];         // 1600000

    float* wsf = nullptr; int* wsi = nullptr;
    hipGetSymbolAddress((void**)&wsf, HIP_SYMBOL(g_wsf));
    hipGetSymbolAddress((void**)&wsi, HIP_SYMBOL(g_wsi));
    float* isq_s = wsf;                      // N
    float* isq_d = wsf + n;                  // N
    float* buf1  = wsf + 2 * (size_t)n;      // N*64
    float* buf2  = buf1 + (size_t)n * 64;    // N*64
    float* stats = buf2 + (size_t)n * 64;    // 256 (stats0 | stats1)
    int* deg_s   = wsi;                      // N
    int* deg_d   = wsi + n;                  // N
    int* cnt     = wsi + 2 * (size_t)n;      // N
    int* row_ptr = wsi + 3 * (size_t)n;      // N+1
    int* col     = wsi + 4 * (size_t)n + 1;  // E

    const int gE = (E + 255) / 256;
    const int gN = (n + 255) / 256;
    const int gW = (n + 3) / 4;              // wave-per-node grids
    const int gNF = (n * 64 + 255) / 256;

    // ---- CSR build + degrees ----
    hipMemsetAsync(deg_s, 0, 3 * (size_t)n * sizeof(int), stream);   // deg_s,deg_d,cnt
    hipMemsetAsync(stats, 0, 256 * sizeof(float), stream);
    k_hist<<<gE, 256, 0, stream>>>(src, dst, deg_s, deg_d, E);
    k_scan<<<1, 1024, 0, stream>>>(deg_d, row_ptr, n);
    k_fill<<<gE, 256, 0, stream>>>(src, dst, row_ptr, cnt, col, E);
    k_isqrt<<<gN, 256, 0, stream>>>(deg_s, deg_d, isq_s, isq_d, n);

    // ---- Layer 0: GEMM (feat*isq_s)@W0, pull-agg (+isq_d+b0), BN, ReLU*isq_s ----
    k_gemm<128, 64, 16, false><<<(n + 15) / 16, 256, 0, stream>>>(feat, isq_s, W0, nullptr, buf1, n);
    k_agg64<true><<<gW, 256, 0, stream>>>(row_ptr, col, buf1, isq_d, b0, buf2, n);
    k_bn_stats<<<512, 256, 0, stream>>>(buf2, stats, n);
    k_bn_apply<<<gNF, 256, 0, stream>>>(buf2, g0, be0, stats, isq_s, buf1, n);

    // ---- Layer 1: pull-agg raw, GEMM (agg*isq_d)@W1+b1, BN, ReLU*isq_s ----
    k_agg64<false><<<gW, 256, 0, stream>>>(row_ptr, col, buf1, nullptr, nullptr, buf2, n);
    k_gemm<64, 64, 16, true><<<(n + 15) / 16, 256, 0, stream>>>(buf2, isq_d, W1, b1, buf1, n);
    k_bn_stats<<<512, 256, 0, stream>>>(buf1, stats + 128, n);
    k_bn_apply<<<gNF, 256, 0, stream>>>(buf1, g1, be1, stats + 128, isq_s, buf2, n);

    // ---- Layer 2: pull-agg raw, GEMM (agg*isq_d)@W2+b2 -> out (f32) ----
    k_agg64<false><<<gW, 256, 0, stream>>>(row_ptr, col, buf2, nullptr, nullptr, buf1, n);
    k_gemm<64, 47, 16, true><<<(n + 15) / 16, 256, 0, stream>>>(buf1, isq_d, W2, b2, (float*)d_out, n);
}